// Round 6
// baseline (296.852 us; speedup 1.0000x reference)
//
#include <hip/hip_runtime.h>
#include <hip/hip_bf16.h>
#include <math.h>

typedef unsigned short u16;
typedef unsigned int u32;
typedef __attribute__((ext_vector_type(8))) short bf16x8;   // 8 bf16 = 4 VGPRs
typedef __attribute__((ext_vector_type(4))) short bf16x4;   // 4 bf16 = 2 VGPRs
typedef __attribute__((ext_vector_type(4))) float f32x4;

#define EMBED 768
#define NHEADS 12
#define HDIM 64
#define NBATCH 2
#define SEQ 2048
#define NTOK 4096
#define QKV_N 2304
#define BHTOT 24        // NBATCH*NHEADS
// Q scale folds softmax's 1/sqrt(d) AND log2(e) so attn can use raw v_exp_f32
#define QSCALE 0.18033688011112042f   // 0.125 * log2(e)

__device__ __forceinline__ u16 f2b(float f) {
    __hip_bfloat16 h = __float2bfloat16(f);
    return __builtin_bit_cast(u16, h);
}
__device__ __forceinline__ u32 pk2(float a, float b) {
    return (u32)f2b(a) | ((u32)f2b(b) << 16);
}
__device__ __forceinline__ f32x4 mfma32(bf16x8 a, bf16x8 b, f32x4 c) {
    return __builtin_amdgcn_mfma_f32_16x16x32_bf16(a, b, c, 0, 0, 0);
}
// K=16 MFMA: B-operand layout == C/D layout -> P feeds PV from registers.
#if __has_builtin(__builtin_amdgcn_mfma_f32_16x16x16_bf16)
__device__ __forceinline__ f32x4 mfma16(bf16x4 a, bf16x4 b, f32x4 c) {
    return __builtin_amdgcn_mfma_f32_16x16x16_bf16(a, b, c, 0, 0, 0);
}
#else
__device__ __forceinline__ f32x4 mfma16(bf16x4 a, bf16x4 b, f32x4 c) {
    return __builtin_amdgcn_mfma_f32_16x16x16bf16_1k(a, b, c, 0, 0, 0);
}
#endif

// guaranteed single-instruction 2^x (never libm)
__device__ __forceinline__ float exp2_hw(float x) {
#if __has_builtin(__builtin_amdgcn_exp2f)
    return __builtin_amdgcn_exp2f(x);
#else
    float r;
    asm("v_exp_f32 %0, %1" : "=v"(r) : "v"(x));
    return r;
#endif
}

// async global->LDS, 16B per lane. LDS dest must be base + lane*16 in lane
// order (HW constraint); our swizzle lives on the GLOBAL address side.
__device__ __forceinline__ void async16(const u16* g, u16* l) {
    __builtin_amdgcn_global_load_lds(
        (const __attribute__((address_space(1))) unsigned int*)g,
        (__attribute__((address_space(3))) unsigned int*)l,
        16, 0, 0);
}

// ---------------------------------------------------------------------------
// fp32 -> bf16 cast for x, w_qkv, w_out
// ---------------------------------------------------------------------------
__global__ __launch_bounds__(256)
void cast_kernel(const float* __restrict__ s0, u16* __restrict__ d0, int n0,
                 const float* __restrict__ s1, u16* __restrict__ d1, int n1,
                 const float* __restrict__ s2, u16* __restrict__ d2, int n2)
{
    int idx = (blockIdx.x * 256 + threadIdx.x) * 4;
    const float* s; u16* d; int i;
    if (idx < n0)            { s = s0; d = d0; i = idx; }
    else if (idx < n0 + n1)  { s = s1; d = d1; i = idx - n0; }
    else                     { s = s2; d = d2; i = idx - n0 - n1; if (i >= n2) return; }
    float4 v = *(const float4*)&s[i];
    ushort4 o;
    o.x = f2b(v.x); o.y = f2b(v.y); o.z = f2b(v.z); o.w = f2b(v.w);
    *(ushort4*)&d[i] = o;
}

// ---------------------------------------------------------------------------
// QKV projection, bf16 MFMA. 128x128 tile, BK=64, NK=12.  (unchanged R1)
// ---------------------------------------------------------------------------
__global__ __launch_bounds__(256)
void qkv_gemm(const u16* __restrict__ A, const u16* __restrict__ W,
              const float* __restrict__ bias,
              u16* __restrict__ Qb, u16* __restrict__ Kb, u16* __restrict__ VT)
{
    __shared__ __align__(16) u16 smem[4 * 8192];   // As[2]|Bs[2] 64KB; reused as T[4][64*72]
    u16* As = smem;                                // [buf][128 rows x 64 cols] swizzled
    u16* Bs = smem + 2 * 8192;
    const int m0 = blockIdx.x * 128;
    const int n0 = blockIdx.y * 128;
    const int tid = threadIdx.x;
    const int w = tid >> 6, l = tid & 63;
    const int c = l & 15, q = l >> 4;
    const int wm = (w >> 1) * 64, wn = (w & 1) * 64;
    const int r8 = l >> 3, ch = l & 7;
    const int gch = ch ^ r8;                       // involution swizzle

    #pragma unroll
    for (int j = 0; j < 4; ++j) {
        int row = w * 32 + j * 8 + r8;
        int seg = (w * 32 + j * 8) * 64;
        async16(&A[(size_t)(m0 + row) * EMBED + gch * 8], &As[seg + l * 8]);
        async16(&W[(size_t)(n0 + row) * EMBED + gch * 8], &Bs[seg + l * 8]);
    }

    f32x4 acc[4][4] = {};
    const int NK = EMBED / 64;   // 12

    #pragma unroll 2
    for (int kt = 0; kt < NK; ++kt) {
        const int cur = kt & 1;
        __syncthreads();          // drains tile kt's loads; prev buffer readers done
        if (kt + 1 < NK) {        // issue kt+1 into the other buffer (lands during compute)
            int k0 = (kt + 1) * 64;
            #pragma unroll
            for (int j = 0; j < 4; ++j) {
                int row = w * 32 + j * 8 + r8;
                int seg = (cur ^ 1) * 8192 + (w * 32 + j * 8) * 64;
                async16(&A[(size_t)(m0 + row) * EMBED + k0 + gch * 8], &As[seg + l * 8]);
                async16(&W[(size_t)(n0 + row) * EMBED + k0 + gch * 8], &Bs[seg + l * 8]);
            }
        }
        const u16* Ab = As + cur * 8192;
        const u16* Bb = Bs + cur * 8192;
        #pragma unroll
        for (int ks = 0; ks < 2; ++ks) {
            const int cs = (((ks << 2) | q) ^ (c & 7)) << 3;   // swizzled chunk
            bf16x8 af[4], bfr[4];
            #pragma unroll
            for (int i = 0; i < 4; ++i)
                af[i] = *(const bf16x8*)&Ab[(wm + i * 16 + c) * 64 + cs];
            #pragma unroll
            for (int j = 0; j < 4; ++j)
                bfr[j] = *(const bf16x8*)&Bb[(wn + j * 16 + c) * 64 + cs];
            #pragma unroll
            for (int i = 0; i < 4; ++i)
                #pragma unroll
                for (int j = 0; j < 4; ++j)
                    acc[i][j] = mfma32(af[i], bfr[j], acc[i][j]);
        }
    }

    const int p = n0 / EMBED;                 // 0=q,1=k,2=v (block-uniform)
    const int ncol0 = n0 + wn;
    const int h = (ncol0 % EMBED) / HDIM;
    const int mrow0 = m0 + wm;
    const int b = mrow0 >> 11;
    const int s0 = mrow0 & (SEQ - 1);

    if (p < 2) {
        u16* dst = (p == 0) ? Qb : Kb;
        const float mul = (p == 0) ? QSCALE : 1.0f;
        #pragma unroll
        for (int j = 0; j < 4; ++j) {
            int n = ncol0 + j * 16 + c;
            int d = j * 16 + c;
            float bval = bias[n];
            #pragma unroll
            for (int i = 0; i < 4; ++i) {
                #pragma unroll
                for (int r = 0; r < 4; ++r) {
                    int s = s0 + i * 16 + q * 4 + r;
                    float v = (acc[i][j][r] + bval) * mul;
                    dst[(((size_t)(b * NHEADS + h)) * SEQ + s) * HDIM + d] = f2b(v);
                }
            }
        }
    } else {
        __syncthreads();                      // all MFMA LDS reads done
        u16* T = smem + w * (64 * 72);        // wave-private scratch
        #pragma unroll
        for (int j = 0; j < 4; ++j) {
            int n = ncol0 + j * 16 + c;
            float bval = bias[n];
            #pragma unroll
            for (int i = 0; i < 4; ++i) {
                uint2 pr;
                pr.x = pk2(acc[i][j][0] + bval, acc[i][j][1] + bval);
                pr.y = pk2(acc[i][j][2] + bval, acc[i][j][3] + bval);
                *(uint2*)&T[(j * 16 + c) * 72 + i * 16 + q * 4] = pr;
            }
        }
        const size_t vtbase = ((size_t)(b * NHEADS + h)) * HDIM * SEQ + s0;
        #pragma unroll
        for (int ii = 0; ii < 8; ++ii) {
            int d = (l >> 3) + 8 * ii;
            int sch = (l & 7) * 8;
            uint4 vv = *(const uint4*)&T[d * 72 + sch];
            *(uint4*)&VT[vtbase + (size_t)d * SEQ + sch] = vv;
        }
    }
}

// ---------------------------------------------------------------------------
// Flash attention R6: TLP-FIRST restructure. R2/R3/R5 all ~47-54us with every
// pipe <=42% and 3 blocks/CU (48KB LDS cap) -> latency-bound, occupancy is
// the lever. This version: 32-row q-tiles -> 1536 blocks = 6/CU perfect fill.
// V moves from LDS to REGISTERS (per-wave global uint2 loads, L2-hot, issued
// at body start and covered by QK^T); K stays in LDS, NBUF=3 = 24KB total ->
// 6 blocks/CU by LDS. Wave (wq,wk) owns 16 qrows x 32 keys. ~80 persistent
// VGPR (o16+bq8+vr16+sc8) -> no spill (R4 lesson; launch_bounds(256,5) caps
// alloc at 102, actual <=85 packs 6 blocks).
// Body j: [V(j) reg loads][vmcnt(10): K(j) landed, K(j+1)+V(j) fly][barrier]
//         [stage K(j+2): slot free, readers of K(j-1) are past the barrier]
//         [QK^T(j)][compiler-counted vmcnt for V][softmax+PV from regs]
// K slots rotate mod 3 via pointer arithmetic (no register-array indexing).
// ---------------------------------------------------------------------------
__global__ __launch_bounds__(256, 5)
void attn_kernel(const u16* __restrict__ Qb, const u16* __restrict__ Kb,
                 const u16* __restrict__ VT, u16* __restrict__ AO)
{
    __shared__ __align__(16) u16 Ks[3][4096];   // 24KB: [buf][64 keys x 64 d] swizzled

    const int blk = blockIdx.x;                 // 1536
    const int g = blk & 7, kk = blk >> 3;       // XCD round-robin; 192 per XCD
    const int bh = g * 3 + (kk >> 6);           // 3 bh per XCD (KV L2 locality)
    const int qt = kk & 63;                     // 64 q-tiles of 32 rows

    const int tid = threadIdx.x;
    const int w = tid >> 6, l = tid & 63;
    const int c = l & 15, q = l >> 4;
    const int wq = w >> 1, wk = w & 1;          // q-half, key-half

    const u16* qg = Qb + ((size_t)bh * SEQ + qt * 32 + wq * 16) * HDIM;
    const u16* kg = Kb + ((size_t)bh * SEQ) * HDIM;
    const u16* vg = VT + ((size_t)bh * HDIM) * SEQ + wk * 32 + q * 4;

    // K staging geometry: wave w fills rows [w*16, w*16+16); swizzle on the
    // global chunk (involution): LDS[row][ch] = global[row][ch ^ (row&7)].
    const int r8 = l >> 3, ch = l & 7;
    const int gch = ch ^ r8;

    // Q^T B-fragments (8 VGPR): rows wq*16+c, d = q*8.. and 32+q*8..
    bf16x8 bq0 = *(const bf16x8*)&qg[c * HDIM + q * 8];
    bf16x8 bq1 = *(const bf16x8*)&qg[c * HDIM + 32 + q * 8];

    f32x4 o[4] = {};          // [db] O^T partial over this wave's 32-key slice
    float lrow = 0.f;

    const int NT = SEQ / 64;  // 32 key-tiles

    // prologue: stage K tiles 0,1 (2 async16 each per wave)
    {
        int row0 = w * 16 + r8;
        async16(&kg[(size_t)(row0     ) * HDIM + gch * 8], &Ks[0][(w * 16    ) * 64 + l * 8]);
        async16(&kg[(size_t)(row0 +  8) * HDIM + gch * 8], &Ks[0][(w * 16 + 8) * 64 + l * 8]);
        async16(&kg[(size_t)(64 + row0    ) * HDIM + gch * 8], &Ks[1][(w * 16    ) * 64 + l * 8]);
        async16(&kg[(size_t)(64 + row0 + 8) * HDIM + gch * 8], &Ks[1][(w * 16 + 8) * 64 + l * 8]);
    }

    const u16* kbase = &Ks[0][0];
    int sR = 0, sW = 2;       // read slot j%3, stage slot (j+2)%3  (x4096 u16)

    for (int j = 0; j < NT; ++j) {
        // 1. V(j) -> registers: av(db,kb2) = V^T[db*16+c][j*64 + wk*32 + kb2*16 + q*4 ..+3]
        uint2 vr[4][2];
        #pragma unroll
        for (int db = 0; db < 4; ++db)
            #pragma unroll
            for (int kb2 = 0; kb2 < 2; ++kb2)
                vr[db][kb2] = *(const uint2*)&vg[(size_t)(db * 16 + c) * SEQ + j * 64 + kb2 * 16];

        // 2. K(j) landed (staged 2 barriers ago); K(j+1)'s 2 + V(j)'s 8 keep flying
        asm volatile("s_waitcnt vmcnt(10)" ::: "memory");
        __builtin_amdgcn_s_barrier();

        // 3. stage K(j+2): its slot held K(j-1), whose readers are past the barrier
        if (j + 2 < NT) {
            int row0 = w * 16 + r8;
            u16* kst = (u16*)kbase + sW * 4096;
            async16(&kg[(size_t)((j + 2) * 64 + row0     ) * HDIM + gch * 8],
                    &kst[(w * 16    ) * 64 + l * 8]);
            async16(&kg[(size_t)((j + 2) * 64 + row0 +  8) * HDIM + gch * 8],
                    &kst[(w * 16 + 8) * 64 + l * 8]);
        }

        // 4. S^T slice = K·Q^T over this wave's 32 keys (2 kb2 x K=32)
        const u16* kr = kbase + sR * 4096;
        f32x4 sc[2];
        __builtin_amdgcn_s_setprio(1);
        #pragma unroll
        for (int kb2 = 0; kb2 < 2; ++kb2) {
            bf16x8 ak0 = *(const bf16x8*)&kr[(wk * 32 + kb2 * 16 + c) * 64 +
                                             (((q    ) ^ (c & 7)) << 3)];
            bf16x8 ak1 = *(const bf16x8*)&kr[(wk * 32 + kb2 * 16 + c) * 64 +
                                             (((q | 4) ^ (c & 7)) << 3)];
            f32x4 zz = {};
            zz = mfma32(ak0, bq0, zz);
            sc[kb2] = mfma32(ak1, bq1, zz);
        }
        __builtin_amdgcn_s_setprio(0);

        // 5. exp2 softmax (log2e folded into Q), P->bf16 B-frags
        bf16x4 bp[2];
        #pragma unroll
        for (int kb2 = 0; kb2 < 2; ++kb2) {
            float p0 = exp2_hw(sc[kb2][0]);
            float p1 = exp2_hw(sc[kb2][1]);
            float p2 = exp2_hw(sc[kb2][2]);
            float p3 = exp2_hw(sc[kb2][3]);
            lrow += (p0 + p1) + (p2 + p3);
            uint2 pr;
            pr.x = pk2(p0, p1);
            pr.y = pk2(p2, p3);
            bp[kb2] = __builtin_bit_cast(bf16x4, pr);
        }

        // 6. O^T += V^T·P^T from registers (compiler inserts counted vmcnt for vr)
        __builtin_amdgcn_s_setprio(1);
        #pragma unroll
        for (int db = 0; db < 4; ++db) {
            f32x4 t = o[db];
            t = mfma16(__builtin_bit_cast(bf16x4, vr[db][0]), bp[0], t);
            t = mfma16(__builtin_bit_cast(bf16x4, vr[db][1]), bp[1], t);
            o[db] = t;
        }
        __builtin_amdgcn_s_setprio(0);

        sR = (sR == 2) ? 0 : sR + 1;
        sW = (sW == 2) ? 0 : sW + 1;
    }

    // ---- cross-wave reduction: wk-pairs combine 32-key partials ----
    lrow += __shfl_xor(lrow, 16);
    lrow += __shfl_xor(lrow, 32);

    __syncthreads();                     // all K reads + async stages drained
    float* SCR = (float*)&Ks[0][0];      // 8KB O exchange
    float* LR  = SCR + 2048;             // 32 f32 row sums

    if (wk == 1) {                       // push partials
        #pragma unroll
        for (int db = 0; db < 4; ++db)
            *(f32x4*)&SCR[((wq * 4 + db) << 8) + l * 4] = o[db];
        if (q == 0) LR[wq * 16 + c] = lrow;
    }
    __syncthreads();

    if (wk == 0) {                       // add partner, normalize, write AO
        float inv = 1.0f / (lrow + LR[wq * 16 + c]);
        const int b = bh / NHEADS, h = bh % NHEADS;
        const int s = qt * 32 + wq * 16 + c;
        u16* ao = AO + ((size_t)(b * SEQ + s)) * EMBED + h * HDIM;
        #pragma unroll
        for (int db = 0; db < 4; ++db) {
            f32x4 part = *(const f32x4*)&SCR[((wq * 4 + db) << 8) + l * 4];
            f32x4 t = o[db] + part;
            uint2 oo;
            oo.x = pk2(t[0] * inv, t[1] * inv);
            oo.y = pk2(t[2] * inv, t[3] * inv);
            *(uint2*)&ao[db * 16 + q * 4] = oo;
        }
    }
}

// ---------------------------------------------------------------------------
// Output projection, 128x64 tile, BK=64, async double-buffered via
// global_load_lds (same pipeline as qkv_gemm).  (unchanged)
// ---------------------------------------------------------------------------
__global__ __launch_bounds__(256)
void out_gemm(const u16* __restrict__ A, const u16* __restrict__ W,
              const float* __restrict__ bias, float* __restrict__ out)
{
    __shared__ __align__(16) u16 As[2][8192];   // [buf][128 x 64] swizzled
    __shared__ __align__(16) u16 Bs[2][4096];   // [buf][ 64 x 64] swizzled
    const int m0 = blockIdx.x * 128;
    const int n0 = blockIdx.y * 64;
    const int tid = threadIdx.x;
    const int w = tid >> 6, l = tid & 63;
    const int c = l & 15, q = l >> 4;
    const int wm = w * 32;
    const int r8 = l >> 3, ch = l & 7;
    const int gch = ch ^ r8;

    #pragma unroll
    for (int j = 0; j < 4; ++j) {
        int row = w * 32 + j * 8 + r8;
        async16(&A[(size_t)(m0 + row) * EMBED + gch * 8],
                &As[0][(w * 32 + j * 8) * 64 + l * 8]);
    }
    #pragma unroll
    for (int j = 0; j < 2; ++j) {
        int row = w * 16 + j * 8 + r8;
        async16(&W[(size_t)(n0 + row) * EMBED + gch * 8],
                &Bs[0][(w * 16 + j * 8) * 64 + l * 8]);
    }

    f32x4 acc[2][4] = {};
    const int NK = EMBED / 64;   // 12

    #pragma unroll 2
    for (int kt = 0; kt < NK; ++kt) {
        const int cur = kt & 1;
        __syncthreads();
        if (kt + 1 < NK) {
            int k0 = (kt + 1) * 64;
            #pragma unroll
            for (int j = 0; j < 4; ++j) {
                int row = w * 32 + j * 8 + r8;
                async16(&A[(size_t)(m0 + row) * EMBED + k0 + gch * 8],
                        &As[cur ^ 1][(w * 32 + j * 8) * 64 + l * 8]);
            }
            #pragma unroll
            for (int j = 0; j < 2; ++j) {
                int row = w * 16 + j * 8 + r8;
                async16(&W[(size_t)(n0 + row) * EMBED + k0 + gch * 8],
                        &Bs[cur ^ 1][(w * 16 + j * 8) * 64 + l * 8]);
            }
        }
        #pragma unroll
        for (int ks = 0; ks < 2; ++ks) {
            const int cs = (((ks << 2) | q) ^ (c & 7)) << 3;
            bf16x8 af[2], bfr[4];
            #pragma unroll
            for (int i = 0; i < 2; ++i)
                af[i] = *(const bf16x8*)&As[cur][(wm + i * 16 + c) * 64 + cs];
            #pragma unroll
            for (int j = 0; j < 4; ++j)
                bfr[j] = *(const bf16x8*)&Bs[cur][(j * 16 + c) * 64 + cs];
            #pragma unroll
            for (int i = 0; i < 2; ++i)
                #pragma unroll
                for (int j = 0; j < 4; ++j)
                    acc[i][j] = mfma32(af[i], bfr[j], acc[i][j]);
        }
    }

    #pragma unroll
    for (int j = 0; j < 4; ++j) {
        int n = n0 + j * 16 + c;
        float bval = bias[n];
        #pragma unroll
        for (int i = 0; i < 2; ++i) {
            #pragma unroll
            for (int r = 0; r < 4; ++r) {
                int m = m0 + wm + i * 16 + q * 4 + r;
                out[(size_t)m * EMBED + n] = acc[i][j][r] + bval;
            }
        }
    }
}

// ---------------------------------------------------------------------------
extern "C" void kernel_launch(void* const* d_in, const int* in_sizes, int n_in,
                              void* d_out, int out_size, void* d_ws, size_t ws_size,
                              hipStream_t stream)
{
    const float* x    = (const float*)d_in[0];
    const float* wqkv = (const float*)d_in[1];
    const float* bqkv = (const float*)d_in[2];
    const float* wout = (const float*)d_in[3];
    const float* bout = (const float*)d_in[4];
    float* out = (float*)d_out;

    const int nx  = NTOK * EMBED;         // 3,145,728
    const int nwq = QKV_N * EMBED;        // 1,769,472
    const int nwo = EMBED * EMBED;        //   589,824
    const size_t per = (size_t)NBATCH * NHEADS * SEQ * HDIM;  // 3,145,728

    u16* xb    = (u16*)d_ws;
    u16* wqkvb = xb + nx;
    u16* woutb = wqkvb + nwq;
    u16* Qb    = woutb + nwo;
    u16* Kb    = Qb + per;
    u16* VT    = Kb + per;
    u16* AO    = VT + per;   // [token][EMBED] bf16, written directly by attn

    int castTot = (nx + nwq + nwo) / 4;
    cast_kernel<<<castTot / 256, 256, 0, stream>>>(x, xb, nx, wqkv, wqkvb, nwq, wout, woutb, nwo);

    dim3 g1(NTOK / 128, QKV_N / 128);     // (32, 18)
    qkv_gemm<<<g1, 256, 0, stream>>>(xb, wqkvb, bqkv, Qb, Kb, VT);

    attn_kernel<<<BHTOT * 64, 256, 0, stream>>>(Qb, Kb, VT, AO);   // 1536 blocks, 6/CU

    dim3 g3(NTOK / 128, EMBED / 64);      // (32, 12)
    out_gemm<<<g3, 256, 0, stream>>>(AO, woutb, bout, out);
}

// Round 7
// 148.819 us; speedup vs baseline: 1.9947x; 1.9947x over previous
//
#include <hip/hip_runtime.h>
#include <hip/hip_bf16.h>
#include <math.h>

typedef unsigned short u16;
typedef unsigned int u32;
typedef __attribute__((ext_vector_type(8))) short bf16x8;   // 8 bf16 = 4 VGPRs
typedef __attribute__((ext_vector_type(4))) short bf16x4;   // 4 bf16 = 2 VGPRs
typedef __attribute__((ext_vector_type(4))) float f32x4;

#define EMBED 768
#define NHEADS 12
#define HDIM 64
#define NBATCH 2
#define SEQ 2048
#define NTOK 4096
#define QKV_N 2304
#define BHTOT 24        // NBATCH*NHEADS
// Q scale folds softmax's 1/sqrt(d) AND log2(e) so attn can use raw v_exp_f32
#define QSCALE 0.18033688011112042f   // 0.125 * log2(e)

__device__ __forceinline__ u16 f2b(float f) {
    __hip_bfloat16 h = __float2bfloat16(f);
    return __builtin_bit_cast(u16, h);
}
__device__ __forceinline__ u32 pk2(float a, float b) {
    return (u32)f2b(a) | ((u32)f2b(b) << 16);
}
__device__ __forceinline__ f32x4 mfma32(bf16x8 a, bf16x8 b, f32x4 c) {
    return __builtin_amdgcn_mfma_f32_16x16x32_bf16(a, b, c, 0, 0, 0);
}
// K=16 MFMA: B-operand layout == C/D layout -> P feeds PV from registers.
#if __has_builtin(__builtin_amdgcn_mfma_f32_16x16x16_bf16)
__device__ __forceinline__ f32x4 mfma16(bf16x4 a, bf16x4 b, f32x4 c) {
    return __builtin_amdgcn_mfma_f32_16x16x16_bf16(a, b, c, 0, 0, 0);
}
#else
__device__ __forceinline__ f32x4 mfma16(bf16x4 a, bf16x4 b, f32x4 c) {
    return __builtin_amdgcn_mfma_f32_16x16x16bf16_1k(a, b, c, 0, 0, 0);
}
#endif

// guaranteed single-instruction 2^x (never libm)
__device__ __forceinline__ float exp2_hw(float x) {
#if __has_builtin(__builtin_amdgcn_exp2f)
    return __builtin_amdgcn_exp2f(x);
#else
    float r;
    asm("v_exp_f32 %0, %1" : "=v"(r) : "v"(x));
    return r;
#endif
}

// async global->LDS, 16B per lane. LDS dest must be base + lane*16 in lane
// order (HW constraint); our swizzle lives on the GLOBAL address side.
__device__ __forceinline__ void async16(const u16* g, u16* l) {
    __builtin_amdgcn_global_load_lds(
        (const __attribute__((address_space(1))) unsigned int*)g,
        (__attribute__((address_space(3))) unsigned int*)l,
        16, 0, 0);
}

// ---------------------------------------------------------------------------
// fp32 -> bf16 cast for x, w_qkv, w_out
// ---------------------------------------------------------------------------
__global__ __launch_bounds__(256)
void cast_kernel(const float* __restrict__ s0, u16* __restrict__ d0, int n0,
                 const float* __restrict__ s1, u16* __restrict__ d1, int n1,
                 const float* __restrict__ s2, u16* __restrict__ d2, int n2)
{
    int idx = (blockIdx.x * 256 + threadIdx.x) * 4;
    const float* s; u16* d; int i;
    if (idx < n0)            { s = s0; d = d0; i = idx; }
    else if (idx < n0 + n1)  { s = s1; d = d1; i = idx - n0; }
    else                     { s = s2; d = d2; i = idx - n0 - n1; if (i >= n2) return; }
    float4 v = *(const float4*)&s[i];
    ushort4 o;
    o.x = f2b(v.x); o.y = f2b(v.y); o.z = f2b(v.z); o.w = f2b(v.w);
    *(ushort4*)&d[i] = o;
}

// ---------------------------------------------------------------------------
// QKV projection R7: 128x128 tile, BK=32, NK=24. Staging LDS drops 64->32KB
// (T-scratch makes the block 36KB) -> 4 blocks/CU (was 2: occupancy was the
// R1-profiled limiter at 15%). Same async16-after-barrier pipeline.
// 64B rows (4x16B chunks), swizzle ch ^ ((row>>1)&3): each chunk column
// spreads over 16 banks, 2 rows/bank-pair -> 2-way (free).
// Epilogue unchanged: Q(*QSCALE)/K scatter; V transposed through T -> V^T.
// ---------------------------------------------------------------------------
__global__ __launch_bounds__(256, 4)
void qkv_gemm(const u16* __restrict__ A, const u16* __restrict__ W,
              const float* __restrict__ bias,
              u16* __restrict__ Qb, u16* __restrict__ Kb, u16* __restrict__ VT)
{
    __shared__ __align__(16) u16 smem[18432];   // As[2]|Bs[2] staging 32KB; T[4][64*72] 36KB
    u16* As = smem;                             // [buf][128 rows x 32 cols] swizzled
    u16* Bs = smem + 8192;
    const int m0 = blockIdx.x * 128;
    const int n0 = blockIdx.y * 128;
    const int tid = threadIdx.x;
    const int w = tid >> 6, l = tid & 63;
    const int c = l & 15, q = l >> 4;
    const int wm = (w >> 1) * 64, wn = (w & 1) * 64;
    // staging: instr j covers rows j*64 + w*16 + (l>>2); chunk l&3 of 64B row
    const int sr = l >> 2;
    const int gch2 = (l & 3) ^ ((l >> 3) & 3);  // (row>>1)&3 involution swizzle

    // stage K-tile 0 into buffer 0
    #pragma unroll
    for (int j = 0; j < 2; ++j) {
        int row = j * 64 + w * 16 + sr;
        int seg = (j * 64 + w * 16) * 32;
        async16(&A[(size_t)(m0 + row) * EMBED + gch2 * 8], &As[seg + l * 8]);
        async16(&W[(size_t)(n0 + row) * EMBED + gch2 * 8], &Bs[seg + l * 8]);
    }

    f32x4 acc[4][4] = {};
    const int NK = EMBED / 32;   // 24

    #pragma unroll 2
    for (int kt = 0; kt < NK; ++kt) {
        const int cur = kt & 1;
        __syncthreads();          // drains tile kt's loads; prev buffer readers done
        if (kt + 1 < NK) {        // issue kt+1 (lands during compute of kt)
            int k0 = (kt + 1) * 32;
            #pragma unroll
            for (int j = 0; j < 2; ++j) {
                int row = j * 64 + w * 16 + sr;
                int seg = (cur ^ 1) * 4096 + (j * 64 + w * 16) * 32;
                async16(&A[(size_t)(m0 + row) * EMBED + k0 + gch2 * 8], &As[seg + l * 8]);
                async16(&W[(size_t)(n0 + row) * EMBED + k0 + gch2 * 8], &Bs[seg + l * 8]);
            }
        }
        const u16* Ab = As + cur * 4096;
        const u16* Bb = Bs + cur * 4096;
        const int cs = (q ^ ((c >> 1) & 3)) << 3;   // swizzled chunk (full BK=32 row)
        bf16x8 af[4], bfr[4];
        #pragma unroll
        for (int i = 0; i < 4; ++i)
            af[i] = *(const bf16x8*)&Ab[(wm + i * 16 + c) * 32 + cs];
        #pragma unroll
        for (int j = 0; j < 4; ++j)
            bfr[j] = *(const bf16x8*)&Bb[(wn + j * 16 + c) * 32 + cs];
        #pragma unroll
        for (int i = 0; i < 4; ++i)
            #pragma unroll
            for (int j = 0; j < 4; ++j)
                acc[i][j] = mfma32(af[i], bfr[j], acc[i][j]);
    }

    const int p = n0 / EMBED;                 // 0=q,1=k,2=v (block-uniform)
    const int ncol0 = n0 + wn;
    const int h = (ncol0 % EMBED) / HDIM;
    const int mrow0 = m0 + wm;
    const int b = mrow0 >> 11;
    const int s0 = mrow0 & (SEQ - 1);

    if (p < 2) {
        u16* dst = (p == 0) ? Qb : Kb;
        const float mul = (p == 0) ? QSCALE : 1.0f;
        #pragma unroll
        for (int j = 0; j < 4; ++j) {
            int n = ncol0 + j * 16 + c;
            int d = j * 16 + c;
            float bval = bias[n];
            #pragma unroll
            for (int i = 0; i < 4; ++i) {
                #pragma unroll
                for (int r = 0; r < 4; ++r) {
                    int s = s0 + i * 16 + q * 4 + r;
                    float v = (acc[i][j][r] + bval) * mul;
                    dst[(((size_t)(b * NHEADS + h)) * SEQ + s) * HDIM + d] = f2b(v);
                }
            }
        }
    } else {
        __syncthreads();                      // all MFMA LDS reads done
        u16* T = smem + w * (64 * 72);        // wave-private scratch
        #pragma unroll
        for (int j = 0; j < 4; ++j) {
            int n = ncol0 + j * 16 + c;
            float bval = bias[n];
            #pragma unroll
            for (int i = 0; i < 4; ++i) {
                uint2 pr;
                pr.x = pk2(acc[i][j][0] + bval, acc[i][j][1] + bval);
                pr.y = pk2(acc[i][j][2] + bval, acc[i][j][3] + bval);
                *(uint2*)&T[(j * 16 + c) * 72 + i * 16 + q * 4] = pr;
            }
        }
        const size_t vtbase = ((size_t)(b * NHEADS + h)) * HDIM * SEQ + s0;
        #pragma unroll
        for (int ii = 0; ii < 8; ++ii) {
            int d = (l >> 3) + 8 * ii;
            int sch = (l & 7) * 8;
            uint4 vv = *(const uint4*)&T[d * 72 + sch];
            *(uint4*)&VT[vtbase + (size_t)d * SEQ + sch] = vv;
        }
    }
}

// ---------------------------------------------------------------------------
// Flash attention: R5 version restored verbatim (proven 47.5us). 2x2 KEY/Q
// split, V in LDS staged depth-2, software pipeline, NBUF=3, x6 unroll.
// R6's V-in-registers variant regressed 4x: per-body V-load->PV chain with
// only QK^T as cover + scattered 32B segments = serial global latency.
// ---------------------------------------------------------------------------
__global__ __launch_bounds__(256, 3)
void attn_kernel(const u16* __restrict__ Qb, const u16* __restrict__ Kb,
                 const u16* __restrict__ VT, u16* __restrict__ AO)
{
    __shared__ __align__(16) u16 Ks[3][4096];   // [buf][64 keys x 64 d] swizzled
    __shared__ __align__(16) u16 Vs[3][4096];   // [buf][64 d x 64 keys] swizzled

    const int blk = blockIdx.x;
    const int g = blk & 7, kk = blk >> 3;       // g -> XCD (round-robin heuristic)
    const int bh = g * 3 + (kk >> 5);           // same-bh blocks share an XCD (KV L2 reuse)
    const int qt = kk & 31;

    const int tid = threadIdx.x;
    const int w = tid >> 6, l = tid & 63;
    const int c = l & 15, q = l >> 4;
    const int wq = w >> 1, wk = w & 1;          // q-half, key-half

    const u16* qg = Qb + ((size_t)bh * SEQ + qt * 64 + wq * 32) * HDIM;
    const u16* kg = Kb + ((size_t)bh * SEQ) * HDIM;
    const u16* vg = VT + ((size_t)bh * HDIM) * SEQ;

    // async staging geometry: wave w fills rows [w*16, w*16+16) of each tile.
    const int r8 = l >> 3, ch = l & 7;
    const int gch = ch ^ r8;                    // swizzle is an involution

    // Q^T B-fragments for this wave's 2 q-blocks (16 VGPR)
    bf16x8 bq[2][2];
    #pragma unroll
    for (int qb2 = 0; qb2 < 2; ++qb2) {
        bq[qb2][0] = *(const bf16x8*)&qg[(qb2 * 16 + c) * HDIM + q * 8];
        bq[qb2][1] = *(const bf16x8*)&qg[(qb2 * 16 + c) * HDIM + 32 + q * 8];
    }

    f32x4 o[4][2] = {};                 // [db][qb2] partial O^T over 32-key slice
    float lrow[2] = {0.f, 0.f};         // per-qb2 partial row sums

    const int NT = SEQ / 64;   // 32

#define STAGE(JT, BS) {                                                       \
    int row0 = w * 16 + r8;                                                   \
    async16(&kg[(size_t)((JT) * 64 + row0) * HDIM + gch * 8],                 \
            &Ks[BS][(w * 16) * 64 + l * 8]);                                  \
    async16(&vg[(size_t)row0 * SEQ + (JT) * 64 + gch * 8],                    \
            &Vs[BS][(w * 16) * 64 + l * 8]);                                  \
    async16(&kg[(size_t)((JT) * 64 + row0 + 8) * HDIM + gch * 8],             \
            &Ks[BS][(w * 16 + 8) * 64 + l * 8]);                              \
    async16(&vg[(size_t)(row0 + 8) * SEQ + (JT) * 64 + gch * 8],              \
            &Vs[BS][(w * 16 + 8) * 64 + l * 8]);                              \
}

    // S_slice^T[key][qrow]: A = 32 K rows (2 kb2), B = Q^T (2 qb2 blocks)
#define QKT(SN, BN) {                                                         \
    __builtin_amdgcn_s_setprio(1);                                            \
    _Pragma("unroll")                                                         \
    for (int kb2 = 0; kb2 < 2; ++kb2) {                                       \
        bf16x8 ak0 = *(const bf16x8*)&Ks[BN][(wk * 32 + kb2 * 16 + c) * 64 +  \
                                             (((q    ) ^ (c & 7)) << 3)];     \
        bf16x8 ak1 = *(const bf16x8*)&Ks[BN][(wk * 32 + kb2 * 16 + c) * 64 +  \
                                             (((q | 4) ^ (c & 7)) << 3)];     \
        _Pragma("unroll")                                                     \
        for (int qb2 = 0; qb2 < 2; ++qb2) {                                   \
            f32x4 zz = {};                                                    \
            zz = mfma32(ak0, bq[qb2][0], zz);                                 \
            SN[kb2][qb2] = mfma32(ak1, bq[qb2][1], zz);                       \
        }                                                                     \
    }                                                                         \
    __builtin_amdgcn_s_setprio(0);                                            \
}

    // exp2 softmax (log2e folded into Q), P->bf16 frags, O^T += V^T.P^T
#define SOFTPV(SC, BC) {                                                      \
    _Pragma("unroll")                                                         \
    for (int kb2 = 0; kb2 < 2; ++kb2)                                         \
        _Pragma("unroll")                                                     \
        for (int qb2 = 0; qb2 < 2; ++qb2) {                                   \
            float p0 = exp2_hw(SC[kb2][qb2][0]);                              \
            float p1 = exp2_hw(SC[kb2][qb2][1]);                              \
            float p2 = exp2_hw(SC[kb2][qb2][2]);                              \
            float p3 = exp2_hw(SC[kb2][qb2][3]);                              \
            SC[kb2][qb2][0] = p0; SC[kb2][qb2][1] = p1;                       \
            SC[kb2][qb2][2] = p2; SC[kb2][qb2][3] = p3;                       \
            lrow[qb2] += (p0 + p1) + (p2 + p3);                               \
        }                                                                     \
    bf16x4 bp[2][2];                                                          \
    _Pragma("unroll")                                                         \
    for (int kb2 = 0; kb2 < 2; ++kb2)                                         \
        _Pragma("unroll")                                                     \
        for (int qb2 = 0; qb2 < 2; ++qb2) {                                   \
            uint2 pr;                                                         \
            pr.x = pk2(SC[kb2][qb2][0], SC[kb2][qb2][1]);                     \
            pr.y = pk2(SC[kb2][qb2][2], SC[kb2][qb2][3]);                     \
            bp[kb2][qb2] = __builtin_bit_cast(bf16x4, pr);                    \
        }                                                                     \
    __builtin_amdgcn_s_setprio(1);                                            \
    _Pragma("unroll")                                                         \
    for (int db = 0; db < 4; ++db) {                                          \
        bf16x4 av0 = *(const bf16x4*)&Vs[BC][(db * 16 + c) * 64 +             \
                  (((4 * wk     + (q >> 1)) ^ (c & 7)) << 3) + ((q & 1) << 2)]; \
        bf16x4 av1 = *(const bf16x4*)&Vs[BC][(db * 16 + c) * 64 +             \
                  (((4 * wk + 2 + (q >> 1)) ^ (c & 7)) << 3) + ((q & 1) << 2)]; \
        _Pragma("unroll")                                                     \
        for (int qb2 = 0; qb2 < 2; ++qb2) {                                   \
            o[db][qb2] = mfma16(av0, bp[0][qb2], o[db][qb2]);                 \
            o[db][qb2] = mfma16(av1, bp[1][qb2], o[db][qb2]);                 \
        }                                                                     \
    }                                                                         \
    __builtin_amdgcn_s_setprio(0);                                            \
}

#define BODY(J, SC, SN, BC, BN, BS) {                                         \
    asm volatile("s_waitcnt vmcnt(0)" ::: "memory");                          \
    __builtin_amdgcn_s_barrier();                                             \
    if ((J) + 2 < NT) STAGE((J) + 2, BS);                                     \
    if ((J) + 1 < NT) QKT(SN, BN);                                            \
    SOFTPV(SC, BC);                                                           \
}

    f32x4 scA[2][2], scB[2][2];

    // prologue: stage tiles 0,1; compute QK^T(0)
    STAGE(0, 0);
    STAGE(1, 1);
    asm volatile("s_waitcnt vmcnt(4)" ::: "memory");   // tile 0 landed
    __builtin_amdgcn_s_barrier();
    QKT(scA, 0);

    // main: 30 bodies; all buffer/S indices compile-time (x6 unroll)
    for (int jb = 0; jb < 30; jb += 6) {
        BODY(jb + 0, scA, scB, 0, 1, 2);
        BODY(jb + 1, scB, scA, 1, 2, 0);
        BODY(jb + 2, scA, scB, 2, 0, 1);
        BODY(jb + 3, scB, scA, 0, 1, 2);
        BODY(jb + 4, scA, scB, 1, 2, 0);
        BODY(jb + 5, scB, scA, 2, 0, 1);
    }
    // tail: j=30 (stage guard off, computes QK^T(31)), then j=31 (no next)
    BODY(30, scA, scB, 0, 1, 2);
    SOFTPV(scB, 1);                      // j=31: V[31] in buf 31%3==1, landed

#undef STAGE
#undef QKT
#undef SOFTPV
#undef BODY

    // ---- cross-wave reduction: wk-pairs combine 32-key partials ----
    #pragma unroll
    for (int qb2 = 0; qb2 < 2; ++qb2) {
        lrow[qb2] += __shfl_xor(lrow[qb2], 16);
        lrow[qb2] += __shfl_xor(lrow[qb2], 32);
    }

    __syncthreads();                     // all tile LDS reads done; reuse smem
    float* SCR = (float*)&Ks[0][0];      // 16KB O exchange + 256B row sums
    float* LR  = SCR + 4096;

    if (wk == 1) {                       // push partials
        #pragma unroll
        for (int db = 0; db < 4; ++db)
            #pragma unroll
            for (int qb2 = 0; qb2 < 2; ++qb2)
                *(f32x4*)&SCR[((wq * 8 + db * 2 + qb2) << 8) + l * 4] = o[db][qb2];
        if (q == 0) {
            LR[(wq * 2 + 0) * 16 + c] = lrow[0];
            LR[(wq * 2 + 1) * 16 + c] = lrow[1];
        }
    }
    __syncthreads();

    if (wk == 0) {                       // add partner, normalize, write
        float inv[2];
        #pragma unroll
        for (int qb2 = 0; qb2 < 2; ++qb2)
            inv[qb2] = 1.0f / (lrow[qb2] + LR[(wq * 2 + qb2) * 16 + c]);
        const int b = bh / NHEADS, h = bh % NHEADS;
        #pragma unroll
        for (int qb2 = 0; qb2 < 2; ++qb2) {
            const int s = qt * 64 + wq * 32 + qb2 * 16 + c;
            u16* ao = AO + ((size_t)(b * SEQ + s)) * EMBED + h * HDIM;
            #pragma unroll
            for (int db = 0; db < 4; ++db) {
                f32x4 part = *(const f32x4*)&SCR[((wq * 8 + db * 2 + qb2) << 8) + l * 4];
                f32x4 t = o[db][qb2] + part;
                uint2 oo;
                oo.x = pk2(t[0] * inv[qb2], t[1] * inv[qb2]);
                oo.y = pk2(t[2] * inv[qb2], t[3] * inv[qb2]);
                *(uint2*)&ao[db * 16 + q * 4] = oo;
            }
        }
    }
}

// ---------------------------------------------------------------------------
// Output projection R7: 64x64 tile, BK=32 -> grid (64,12)=768 blocks = exactly
// 3/CU balanced (128x64 gave 384 blocks = 1.5/CU, 2-vs-1 makespan imbalance).
// LDS 16KB. Same async16-after-barrier pipeline + (row>>1)&3 chunk swizzle.
// ---------------------------------------------------------------------------
__global__ __launch_bounds__(256)
void out_gemm(const u16* __restrict__ A, const u16* __restrict__ W,
              const float* __restrict__ bias, float* __restrict__ out)
{
    __shared__ __align__(16) u16 As[2][2048];   // [buf][64 rows x 32 cols] swizzled
    __shared__ __align__(16) u16 Bs[2][2048];
    const int m0 = blockIdx.x * 64;
    const int n0 = blockIdx.y * 64;
    const int tid = threadIdx.x;
    const int w = tid >> 6, l = tid & 63;
    const int c = l & 15, q = l >> 4;
    const int sr = l >> 2;
    const int gch2 = (l & 3) ^ ((l >> 3) & 3);  // (row>>1)&3 involution swizzle

    // stage K-tile 0: wave w covers rows w*16..+15 (1 async16 per operand)
    {
        int row = w * 16 + sr;
        async16(&A[(size_t)(m0 + row) * EMBED + gch2 * 8], &As[0][(w * 16) * 32 + l * 8]);
        async16(&W[(size_t)(n0 + row) * EMBED + gch2 * 8], &Bs[0][(w * 16) * 32 + l * 8]);
    }

    f32x4 acc[4] = {};
    const int NK = EMBED / 32;   // 24

    #pragma unroll 2
    for (int kt = 0; kt < NK; ++kt) {
        const int cur = kt & 1;
        __syncthreads();
        if (kt + 1 < NK) {
            int k0 = (kt + 1) * 32;
            int row = w * 16 + sr;
            async16(&A[(size_t)(m0 + row) * EMBED + k0 + gch2 * 8],
                    &As[cur ^ 1][(w * 16) * 32 + l * 8]);
            async16(&W[(size_t)(n0 + row) * EMBED + k0 + gch2 * 8],
                    &Bs[cur ^ 1][(w * 16) * 32 + l * 8]);
        }
        const int cs = (q ^ ((c >> 1) & 3)) << 3;
        bf16x8 af = *(const bf16x8*)&As[cur][(w * 16 + c) * 32 + cs];
        bf16x8 bfr[4];
        #pragma unroll
        for (int j = 0; j < 4; ++j)
            bfr[j] = *(const bf16x8*)&Bs[cur][(j * 16 + c) * 32 + cs];
        #pragma unroll
        for (int j = 0; j < 4; ++j)
            acc[j] = mfma32(af, bfr[j], acc[j]);
    }

    #pragma unroll
    for (int j = 0; j < 4; ++j) {
        int n = n0 + j * 16 + c;
        float bval = bias[n];
        #pragma unroll
        for (int r = 0; r < 4; ++r) {
            int m = m0 + w * 16 + q * 4 + r;
            out[(size_t)m * EMBED + n] = acc[j][r] + bval;
        }
    }
}

// ---------------------------------------------------------------------------
extern "C" void kernel_launch(void* const* d_in, const int* in_sizes, int n_in,
                              void* d_out, int out_size, void* d_ws, size_t ws_size,
                              hipStream_t stream)
{
    const float* x    = (const float*)d_in[0];
    const float* wqkv = (const float*)d_in[1];
    const float* bqkv = (const float*)d_in[2];
    const float* wout = (const float*)d_in[3];
    const float* bout = (const float*)d_in[4];
    float* out = (float*)d_out;

    const int nx  = NTOK * EMBED;         // 3,145,728
    const int nwq = QKV_N * EMBED;        // 1,769,472
    const int nwo = EMBED * EMBED;        //   589,824
    const size_t per = (size_t)NBATCH * NHEADS * SEQ * HDIM;  // 3,145,728

    u16* xb    = (u16*)d_ws;
    u16* wqkvb = xb + nx;
    u16* woutb = wqkvb + nwq;
    u16* Qb    = woutb + nwo;
    u16* Kb    = Qb + per;
    u16* VT    = Kb + per;
    u16* AO    = VT + per;   // [token][EMBED] bf16, written directly by attn

    int castTot = (nx + nwq + nwo) / 4;
    cast_kernel<<<castTot / 256, 256, 0, stream>>>(x, xb, nx, wqkv, wqkvb, nwq, wout, woutb, nwo);

    dim3 g1(NTOK / 128, QKV_N / 128);     // (32, 18)
    qkv_gemm<<<g1, 256, 0, stream>>>(xb, wqkvb, bqkv, Qb, Kb, VT);

    attn_kernel<<<BHTOT * 32, 256, 0, stream>>>(Qb, Kb, VT, AO);   // 768 blocks

    dim3 g3(NTOK / 64, EMBED / 64);       // (64, 12) = 768 blocks, 3/CU balanced
    out_gemm<<<g3, 256, 0, stream>>>(AO, woutb, bout, out);
}